// Round 8
// baseline (317.920 us; speedup 1.0000x reference)
//
#include <hip/hip_runtime.h>
#include <float.h>
#include <math.h>

#define TOKENS 16384
#define HIDDEN 2048
#define NEXP 128
#define TOPK 8
#define NCAND 12
#define DELTA 5e-4f

#define BM 32
#define BK 128
#define KITERS (HIDDEN / BK)   // 16

typedef float f32x16 __attribute__((ext_vector_type(16)));
typedef short bf16x8 __attribute__((ext_vector_type(8)));

__device__ __forceinline__ unsigned pack_hi(float a, float b) {
    return (__float_as_uint(a) >> 16) | (__float_as_uint(b) & 0xFFFF0000u);
}
__device__ __forceinline__ float resid(float a) {
    return a - __uint_as_float(__float_as_uint(a) & 0xFFFF0000u);
}
__device__ __forceinline__ bf16x8 to_hi(float4 a, float4 b) {
    union { unsigned u[4]; bf16x8 v; } r;
    r.u[0] = pack_hi(a.x, a.y); r.u[1] = pack_hi(a.z, a.w);
    r.u[2] = pack_hi(b.x, b.y); r.u[3] = pack_hi(b.z, b.w);
    return r.v;
}
__device__ __forceinline__ bf16x8 to_lo(float4 a, float4 b) {
    union { unsigned u[4]; bf16x8 v; } r;
    r.u[0] = pack_hi(resid(a.x), resid(a.y)); r.u[1] = pack_hi(resid(a.z), resid(a.w));
    r.u[2] = pack_hi(resid(b.x), resid(b.y)); r.u[3] = pack_hi(resid(b.z), resid(b.w));
    return r.v;
}

__device__ __forceinline__ void load_lds_16B(const void* g, void* l) {
    __builtin_amdgcn_global_load_lds(
        (const __attribute__((address_space(1))) unsigned int*)g,
        (__attribute__((address_space(3))) unsigned int*)l, 16, 0, 0);
}

// ---------------------------------------------------------------------------
// K0: pre-split W into slab-ordered bf16 hi/lo fragments for 32x32x16 MFMA.
// 16B chunk id c: lane = c&63; q = c>>6 with
//   q = ((kt*2 + egrp)*32 + s*4 + nt*2 + hl),  kt<16, egrp<2, s<8, nt<2, hl<2
// lane l of chunk: expert = egrp*64 + nt*32 + (l&31), k = kt*128 + s*16 + (l>>5)*8 + j
// ---------------------------------------------------------------------------
__global__ __launch_bounds__(256) void presplit_w(const float* __restrict__ W,
                                                  unsigned short* __restrict__ Ws) {
    const int c = blockIdx.x * 256 + threadIdx.x;   // [0, 65536)
    const int lane = c & 63;
    const int q = c >> 6;
    const int hl = q & 1;
    const int nt = (q >> 1) & 1;
    const int s = (q >> 2) & 7;
    const int egrp = (q >> 5) & 1;
    const int kt = q >> 6;
    const int e = egrp * 64 + nt * 32 + (lane & 31);
    const int k0 = kt * 128 + s * 16 + (lane >> 5) * 8;
    const float* wp = W + (size_t)e * HIDDEN + k0;
    float4 a = *(const float4*)wp;
    float4 b = *(const float4*)(wp + 4);
    uint4 o;
    if (hl) {
        o.x = pack_hi(resid(a.x), resid(a.y)); o.y = pack_hi(resid(a.z), resid(a.w));
        o.z = pack_hi(resid(b.x), resid(b.y)); o.w = pack_hi(resid(b.z), resid(b.w));
    } else {
        o.x = pack_hi(a.x, a.y); o.y = pack_hi(a.z, a.w);
        o.z = pack_hi(b.x, b.y); o.w = pack_hi(b.z, b.w);
    }
    *(uint4*)(Ws + (size_t)c * 8) = o;
}

// ---------------------------------------------------------------------------
// K1: split-bf16 GEMM, 32x32x16 MFMA, K-SPLIT ACROSS WAVES.
// BM=32 x BN=64 x BK=128, grid 1024 (4 blocks/CU, 16 waves/CU). Wave w owns
// k16-chunks s=w*2,w*2+1 each iter and loads its A-frags DIRECTLY from X
// (frag layout: token=lane&31, k=s*16+(lane>>5)*8 -> 64 B/lane/iter), so X is
// read exactly once, there is no sA, no A LDS writes, no A bank conflicts.
// B comes via global_load_lds from pre-split Ws (zero VALU, contiguous).
// Partial accs (per-wave k-slices) are reduced through LDS at the end.
// ---------------------------------------------------------------------------
__global__ __launch_bounds__(256, 4) void router_gemm(const float* __restrict__ X,
                                                      const unsigned short* __restrict__ Ws,
                                                      float* __restrict__ logits) {
    __shared__ unsigned short sB[32 * 512];   // 32 KB: chunk c = s*4+nt*2+hl
    const int tid = threadIdx.x;
    const int lane = tid & 63;
    const int w = tid >> 6;                   // wave = k-slice
    const int t0 = (blockIdx.x >> 1) * BM;
    const int egrp = blockIdx.x & 1;

    // A source: lane -> token t0+(lane&31), k base = w*32 + (lane>>5)*8
    const float* Xp = X + (size_t)(t0 + (lane & 31)) * HIDDEN + w * 32 + ((lane >> 5) * 8);

    f32x16 acc[2];
#pragma unroll
    for (int nt = 0; nt < 2; ++nt)
#pragma unroll
        for (int r = 0; r < 16; ++r) acc[nt][r] = 0.f;

    // X prefetch for iter 0: halves 0/1 at +0,+4 and +16,+20
    float4 xv[4];
    xv[0] = *(const float4*)(Xp);
    xv[1] = *(const float4*)(Xp + 4);
    xv[2] = *(const float4*)(Xp + 16);
    xv[3] = *(const float4*)(Xp + 20);

#pragma unroll 1
    for (int kt = 0; kt < KITERS; ++kt) {
        __syncthreads();   // all waves done reading sB(kt-1)
        // B DMA: wave stages its own 8 chunks (s=w*2..w*2+1 x nt x hl)
        {
            const unsigned short* src =
                Ws + ((size_t)((kt * 2 + egrp) * 32 + w * 8)) * 512 + lane * 8;
            unsigned short* dst = &sB[(w * 8) * 512];
#pragma unroll
            for (int i = 0; i < 8; ++i)
                load_lds_16B(src + i * 512, dst + i * 512);
        }
        __syncthreads();   // drain DMA (same-iter issue->drain)

        float4 xn[4];
        if (kt + 1 < KITERS) {   // X prefetch lands under the MFMAs below
            const float* xp = Xp + (kt + 1) * BK;
            xn[0] = *(const float4*)(xp);
            xn[1] = *(const float4*)(xp + 4);
            xn[2] = *(const float4*)(xp + 16);
            xn[3] = *(const float4*)(xp + 20);
        }

        // compute: 2 halves x 2 nt x 3 split-terms = 12 MFMA, 8 ds_read_b128
#pragma unroll
        for (int h = 0; h < 2; ++h) {
            const bf16x8 ah = to_hi(xv[h * 2], xv[h * 2 + 1]);
            const bf16x8 al = to_lo(xv[h * 2], xv[h * 2 + 1]);
#pragma unroll
            for (int nt = 0; nt < 2; ++nt) {
                const int bb = ((w * 2 + h) * 4 + nt * 2) * 512 + lane * 8;
                const bf16x8 bh = *(const bf16x8*)&sB[bb];
                const bf16x8 bl = *(const bf16x8*)&sB[bb + 512];
                acc[nt] = __builtin_amdgcn_mfma_f32_32x32x16_bf16(ah, bh, acc[nt], 0, 0, 0);
                acc[nt] = __builtin_amdgcn_mfma_f32_32x32x16_bf16(ah, bl, acc[nt], 0, 0, 0);
                acc[nt] = __builtin_amdgcn_mfma_f32_32x32x16_bf16(al, bh, acc[nt], 0, 0, 0);
            }
        }
#pragma unroll
        for (int i = 0; i < 4; ++i) xv[i] = xn[i];
    }

    // ---- cross-wave k-reduction via LDS (sB dead). Layout interleaved for
    // conflict-free b128: float offset = ((w-1)*8 + nt*4 + i)*256 + lane*4.
    __syncthreads();
    float* red = (float*)sB;
    if (w > 0) {
#pragma unroll
        for (int nt = 0; nt < 2; ++nt)
#pragma unroll
            for (int i = 0; i < 4; ++i) {
                float4 v = {acc[nt][i * 4 + 0], acc[nt][i * 4 + 1],
                            acc[nt][i * 4 + 2], acc[nt][i * 4 + 3]};
                *(float4*)&red[(((w - 1) * 8 + nt * 4 + i) * 256) + lane * 4] = v;
            }
    }
    __syncthreads();
    if (w == 0) {
#pragma unroll
        for (int src = 0; src < 3; ++src)
#pragma unroll
            for (int nt = 0; nt < 2; ++nt)
#pragma unroll
                for (int i = 0; i < 4; ++i) {
                    const float4 v = *(const float4*)&red[((src * 8 + nt * 4 + i) * 256) + lane * 4];
                    acc[nt][i * 4 + 0] += v.x; acc[nt][i * 4 + 1] += v.y;
                    acc[nt][i * 4 + 2] += v.z; acc[nt][i * 4 + 3] += v.w;
                }
        // C/D: col=lane&31, row=(reg&3)+8*(reg>>2)+4*(lane>>5)  (verified r6/r7)
        const int col = lane & 31;
        const int rbase = 4 * (lane >> 5);
#pragma unroll
        for (int nt = 0; nt < 2; ++nt) {
            const int e = egrp * 64 + nt * 32 + col;
#pragma unroll
            for (int reg = 0; reg < 16; ++reg) {
                const int row = (reg & 3) + 8 * (reg >> 2) + rbase;
                logits[(size_t)(t0 + row) * NEXP + e] = acc[nt][reg];
            }
        }
    }
}

// ---------------------------------------------------------------------------
// slow path: full-wave exact fp64 refine of one token (round-7 verified).
// ---------------------------------------------------------------------------
__device__ void slow_token(const float* __restrict__ lrow,
                           const float* __restrict__ X,
                           const float* __restrict__ W,
                           float* __restrict__ top_vals,
                           float* __restrict__ top_idx,
                           int t, int lane) {
    const float l0 = lrow[lane];
    const float l1 = lrow[lane + 64];
    bool r0 = false, r1 = false;
    float vals[NCAND]; int idxs[NCAND];
#pragma unroll
    for (int it = 0; it < NCAND; ++it) {
        const float c0 = r0 ? -FLT_MAX : l0;
        const float c1 = r1 ? -FLT_MAX : l1;
        float v; int id;
        if (c1 > c0) { v = c1; id = lane + 64; }
        else         { v = c0; id = lane; }
#pragma unroll
        for (int off = 1; off < 64; off <<= 1) {
            const float ov = __shfl_xor(v, off);
            const int   oi = __shfl_xor(id, off);
            if (ov > v || (ov == v && oi < id)) { v = ov; id = oi; }
        }
        vals[it] = v; idxs[it] = id;
        if (id == lane) r0 = true;
        else if (id == lane + 64) r1 = true;
    }

    const float* xr = X + (size_t)t * HIDDEN;
    double xd[32];
#pragma unroll
    for (int j = 0; j < 8; ++j) {
        const float4 v = *(const float4*)(xr + j * 256 + lane * 4);
        xd[j * 4 + 0] = (double)v.x; xd[j * 4 + 1] = (double)v.y;
        xd[j * 4 + 2] = (double)v.z; xd[j * 4 + 3] = (double)v.w;
    }
    double acc[NCAND];
#pragma unroll
    for (int c = 0; c < NCAND; ++c) {
        const float* wr = W + (size_t)idxs[c] * HIDDEN;
        double a0 = 0.0, a1 = 0.0;
#pragma unroll
        for (int j = 0; j < 8; ++j) {
            const float4 wv = *(const float4*)(wr + j * 256 + lane * 4);
            a0 = fma((double)wv.x, xd[j * 4 + 0], a0);
            a1 = fma((double)wv.y, xd[j * 4 + 1], a1);
            a0 = fma((double)wv.z, xd[j * 4 + 2], a0);
            a1 = fma((double)wv.w, xd[j * 4 + 3], a1);
        }
        acc[c] = a0 + a1;
    }
#pragma unroll
    for (int c = 0; c < NCAND; ++c)
#pragma unroll
        for (int off = 1; off < 64; off <<= 1)
            acc[c] += __shfl_xor(acc[c], off);

    int rank[NCAND];
#pragma unroll
    for (int c = 0; c < NCAND; ++c) {
        int r = 0;
#pragma unroll
        for (int m = 0; m < NCAND; ++m)
            if (acc[m] > acc[c] || (acc[m] == acc[c] && idxs[m] < idxs[c])) ++r;
        rank[c] = r;
    }
    double vmax = acc[0];
#pragma unroll
    for (int c = 0; c < NCAND; ++c) if (rank[c] == 0) vmax = acc[c];
    float e[NCAND], s = 0.f;
#pragma unroll
    for (int c = 0; c < NCAND; ++c) {
        e[c] = (rank[c] < TOPK) ? expf((float)(acc[c] - vmax)) : 0.f;
        s += e[c];
    }
    const float inv = 1.f / s;
    if (lane == 0) {
#pragma unroll
        for (int c = 0; c < NCAND; ++c)
            if (rank[c] < TOPK) {
                top_vals[(size_t)t * TOPK + rank[c]] = e[c] * inv;
                top_idx[(size_t)t * TOPK + rank[c]] = (float)idxs[c];
            }
    }
}

// ---------------------------------------------------------------------------
// K2: topk, 2 tokens per wave. Half-wave (32 lanes, 4 logits/lane) butterfly
// top-9 with 5 shuffle steps (off<=16 stays in half). Clean halves write
// outputs; flagged tokens (rare) take the full-wave fp64 slow path.
// ---------------------------------------------------------------------------
__global__ __launch_bounds__(256) void router_topk(const float* __restrict__ logits,
                                                   const float* __restrict__ X,
                                                   const float* __restrict__ W,
                                                   float* __restrict__ top_vals,
                                                   float* __restrict__ top_idx) {
    const int lane = threadIdx.x & 63;
    const int h = lane >> 5;            // half: token select
    const int li = lane & 31;
    const int tbase = blockIdx.x * 8 + (threadIdx.x >> 6) * 2;
    const int t = tbase + h;
    const float* lrow = logits + (size_t)t * NEXP;

    float v0 = lrow[li];
    float v1 = lrow[li + 32];
    float v2 = lrow[li + 64];
    float v3 = lrow[li + 96];
    bool rm0 = false, rm1 = false, rm2 = false, rm3 = false;

    float vals[TOPK + 1]; int idxs[TOPK + 1];
#pragma unroll
    for (int it = 0; it < TOPK + 1; ++it) {
        // local argmax over 4 slots, earlier slot (lower expert) wins ties
        float bv = rm0 ? -FLT_MAX : v0; int bs = 0;
        const float c1 = rm1 ? -FLT_MAX : v1;
        const float c2 = rm2 ? -FLT_MAX : v2;
        const float c3 = rm3 ? -FLT_MAX : v3;
        if (c1 > bv) { bv = c1; bs = 1; }
        if (c2 > bv) { bv = c2; bs = 2; }
        if (c3 > bv) { bv = c3; bs = 3; }
        int id = bs * 32 + li;
#pragma unroll
        for (int off = 1; off < 32; off <<= 1) {
            const float ov = __shfl_xor(bv, off);
            const int   oi = __shfl_xor(id, off);
            if (ov > bv || (ov == bv && oi < id)) { bv = ov; id = oi; }
        }
        vals[it] = bv; idxs[it] = id;
        if ((id & 31) == li) {
            const int s = id >> 5;
            rm0 |= (s == 0); rm1 |= (s == 1); rm2 |= (s == 2); rm3 |= (s == 3);
        }
    }

    float ming = FLT_MAX;
#pragma unroll
    for (int i = 0; i < TOPK; ++i) ming = fminf(ming, vals[i] - vals[i + 1]);
    const bool flag = (ming < DELTA);     // half-uniform

    if (!flag && li == 0) {
        const float m = vals[0];
        float ex[TOPK], s = 0.f;
#pragma unroll
        for (int i = 0; i < TOPK; ++i) { ex[i] = expf(vals[i] - m); s += ex[i]; }
        const float inv = 1.f / s;
#pragma unroll
        for (int i = 0; i < TOPK; ++i) {
            top_vals[(size_t)t * TOPK + i] = ex[i] * inv;
            top_idx[(size_t)t * TOPK + i] = (float)idxs[i];
        }
    }

    const unsigned long long bal = __ballot(flag);
    if (bal & 1ull)
        slow_token(logits + (size_t)tbase * NEXP, X, W, top_vals, top_idx, tbase, lane);
    if (bal & (1ull << 32))
        slow_token(logits + (size_t)(tbase + 1) * NEXP, X, W, top_vals, top_idx, tbase + 1, lane);
}

extern "C" void kernel_launch(void* const* d_in, const int* in_sizes, int n_in,
                              void* d_out, int out_size, void* d_ws, size_t ws_size,
                              hipStream_t stream) {
    const float* X = (const float*)d_in[0];   // [16384, 2048] f32
    const float* W = (const float*)d_in[1];   // [128, 2048] f32
    float* logits = (float*)d_out;                          // [16384,128]
    float* tvals  = logits + (size_t)TOKENS * NEXP;         // [16384,8]
    float* tidx   = tvals + (size_t)TOKENS * TOPK;          // [16384,8]

    unsigned short* Wsplit = (unsigned short*)d_ws;         // 1 MB

    presplit_w<<<256, 256, 0, stream>>>(W, Wsplit);
    router_gemm<<<(TOKENS / BM) * 2, 256, 0, stream>>>(X, Wsplit, logits);
    router_topk<<<TOKENS / 8, 256, 0, stream>>>(logits, X, W, tvals, tidx);
}